// Round 7
// baseline (1839.576 us; speedup 1.0000x reference)
//
#include <hip/hip_runtime.h>
#include <stdint.h>

#define SEQ   2048
#define DIM   64
#define BH    48
#define NELEM (BH*SEQ*DIM)          // 6291456
#define NTILE (BH*(SEQ/16))         // 6144 q-tiles
#define ATTN_F4 ((size_t)BH*SEQ*SEQ/4)   // 50331648 float4s in attn

typedef __attribute__((ext_vector_type(4))) float f32x4;
typedef __attribute__((ext_vector_type(8))) short bf16x8;

#define MFMA_BF16 __builtin_amdgcn_mfma_f32_16x16x32_bf16

static __device__ __forceinline__ unsigned short f2bf(float x){
  unsigned int u = __float_as_uint(x);
  u += 0x7fffu + ((u >> 16) & 1u);
  return (unsigned short)(u >> 16);
}
static __device__ __forceinline__ float bf2f(unsigned int h){
  return __uint_as_float(h << 16);
}

// ---------------- prep: K -> (Khi, Klo) bf16 split ----------------
__global__ void prep_split_k(const float* __restrict__ K,
                             unsigned short* __restrict__ Khi,
                             unsigned short* __restrict__ Klo){
  const int n4 = NELEM/4;
  for (int i = blockIdx.x*blockDim.x + threadIdx.x; i < n4; i += gridDim.x*blockDim.x){
    float4 k = ((const float4*)K)[i];
    float kv[4] = {k.x,k.y,k.z,k.w};
    unsigned short h[4], lo[4];
    #pragma unroll
    for (int j=0;j<4;++j){
      h[j]  = f2bf(kv[j]);
      lo[j] = f2bf(kv[j] - bf2f(h[j]));
    }
    uint2 hp, lp;
    hp.x = (unsigned)h[0]  | ((unsigned)h[1]<<16);
    hp.y = (unsigned)h[2]  | ((unsigned)h[3]<<16);
    lp.x = (unsigned)lo[0] | ((unsigned)lo[1]<<16);
    lp.y = (unsigned)lo[2] | ((unsigned)lo[3]<<16);
    ((uint2*)Khi)[i] = hp;
    ((uint2*)Klo)[i] = lp;
  }
}

// ---------------- prep: V -> Vt bf16 transposed [bh][d][s] ----------------
__global__ void prep_transpose_v(const float* __restrict__ V,
                                 unsigned short* __restrict__ Vt){
  __shared__ float tile[64][65];
  int bh = blockIdx.x >> 5;          // 32 s-chunks of 64
  int s0 = (blockIdx.x & 31) << 6;
  int t  = threadIdx.x;              // 256 threads
  const float* Vb = V + ((size_t)bh*SEQ + s0)*DIM;
  #pragma unroll
  for (int r=0;r<4;++r){
    int f = r*1024 + t*4;
    int s = f >> 6, d = f & 63;
    float4 v = *(const float4*)(Vb + f);
    tile[s][d+0]=v.x; tile[s][d+1]=v.y; tile[s][d+2]=v.z; tile[s][d+3]=v.w;
  }
  __syncthreads();
  int d = t >> 2, si = (t & 3) << 4;
  unsigned int o[8];
  #pragma unroll
  for (int u=0;u<8;++u){
    unsigned short a = f2bf(tile[si+2*u  ][d]);
    unsigned short b = f2bf(tile[si+2*u+1][d]);
    o[u] = (unsigned)a | ((unsigned)b<<16);
  }
  unsigned short* orow = Vt + (size_t)bh*DIM*SEQ + (size_t)d*SEQ + s0 + si;
  uint4 p0 = make_uint4(o[0],o[1],o[2],o[3]);
  uint4 p1 = make_uint4(o[4],o[5],o[6],o[7]);
  ((uint4*)orow)[0] = p0;
  ((uint4*)orow)[1] = p1;
}

// Q fragment loader
static __device__ __forceinline__ void load_q_hilo(const float* Qrow, bf16x8* qh, bf16x8* ql){
  #pragma unroll
  for (int ks=0; ks<2; ++ks){
    float4 a = *(const float4*)(Qrow + ks*32);
    float4 b = *(const float4*)(Qrow + ks*32 + 4);
    float x[8] = {a.x,a.y,a.z,a.w,b.x,b.y,b.z,b.w};
    #pragma unroll
    for (int j=0;j<8;++j){
      float v = x[j]*0.125f;
      unsigned short h = f2bf(v);
      qh[ks][j] = (short)h;
      ql[ks][j] = (short)f2bf(v - bf2f(h));
    }
  }
}

// ================= PROBE 1: ideal-pattern linear store, 805 MB =================
__global__ __launch_bounds__(256) void probe_store_linear(float* __restrict__ dst){
  f32x4 v = {1.f, 1.f, 1.f, 1.f};
  size_t stride = (size_t)gridDim.x*blockDim.x;
  for (size_t i = (size_t)blockIdx.x*blockDim.x + threadIdx.x; i < ATTN_F4; i += stride)
    __builtin_nontemporal_store(v, ((f32x4*)dst) + i);
}

// ============ PROBE 2: exact attn-store addressing, no compute, 805 MB ==========
__global__ __launch_bounds__(256, 4) void probe_store_pattern(float* __restrict__ attn_out){
  int tid = threadIdx.x;
  int w = tid >> 6, l = tid & 63;
  int lr = l & 15, lg = l >> 4;
  int bid = blockIdx.x;
  int swz = (bid & 7)*(NTILE/8) + (bid >> 3);
  int bh = swz >> 7;
  int q0 = (swz & 127) << 4;
  size_t bhq = (size_t)bh*SEQ;
  float* attn_row = attn_out + (bhq + q0 + lr)*SEQ;
  int kvbase = w*512;
  f32x4 v = {1.f, 1.f, 1.f, 1.f};
  for (int c=0; c<16; ++c){
    int kvc = kvbase + c*32;
    __builtin_nontemporal_store(v, (f32x4*)(attn_row + kvc + 4*lg));
    __builtin_nontemporal_store(v, (f32x4*)(attn_row + kvc + 16 + 4*lg));
  }
}

// ====== PROBE 3: attn_fused with ALL global stores -> asm keepalive (no DCE) =====
__global__ __launch_bounds__(256, 4) void probe_compute_nostore(
    const float* __restrict__ Q,
    const unsigned short* __restrict__ Khi,
    const unsigned short* __restrict__ Klo,
    const unsigned short* __restrict__ Vt){

  __shared__ float red[64];
  __shared__ float ctile[3072];

  int tid = threadIdx.x;
  int w = tid >> 6, l = tid & 63;
  int lr = l & 15, lg = l >> 4;

  int bid = blockIdx.x;
  int swz = (bid & 7)*(NTILE/8) + (bid >> 3);
  int bh = swz >> 7;
  int q0 = (swz & 127) << 4;
  size_t bhq = (size_t)bh*SEQ;

  bf16x8 qh[2], ql[2];
  load_q_hilo(Q + (bhq + q0 + lr)*DIM + lg*8, qh, ql);

  const unsigned short* Khb = Khi + bhq*DIM;
  const unsigned short* Klb = Klo + bhq*DIM;
  const unsigned short* Vtb = Vt  + bhq*DIM;
  const int kvbase = w*512;

  float rs = 0.f;
  #pragma unroll 2
  for (int t=0; t<16; ++t){
    int kv0 = kvbase + t*32;
    const unsigned short* kr = Khb + (size_t)(kv0 + lr)*DIM + lg*8;
    bf16x8 kh0 = *(const bf16x8*)kr;
    bf16x8 kh1 = *(const bf16x8*)(kr + 32);
    bf16x8 kh0B = *(const bf16x8*)(kr + 16*DIM);
    bf16x8 kh1B = *(const bf16x8*)(kr + 16*DIM + 32);
    f32x4 a = {0,0,0,0}, b = {0,0,0,0};
    a = MFMA_BF16(kh0,  qh[0], a, 0,0,0);
    a = MFMA_BF16(kh1,  qh[1], a, 0,0,0);
    b = MFMA_BF16(kh0B, qh[0], b, 0,0,0);
    b = MFMA_BF16(kh1B, qh[1], b, 0,0,0);
    #pragma unroll
    for (int r=0;r<4;++r) rs += __expf(a[r]) + __expf(b[r]);
  }
  rs += __shfl_xor(rs, 16, 64);
  rs += __shfl_xor(rs, 32, 64);
  if (l < 16) red[w*16 + l] = rs;
  __syncthreads();
  float rv = 1.0f/(red[lr] + red[16+lr] + red[32+lr] + red[48+lr] + 1e-8f);

  f32x4 o0={0,0,0,0}, o1={0,0,0,0}, o2={0,0,0,0}, o3={0,0,0,0};
  int src0 = lr + ((lg & 1) ? 32 : 0);
  int src1 = src0 + 16;
  bool losel = (lg < 2);

  for (int c=0; c<16; ++c){
    int kvc = kvbase + c*32;

    bf16x8 vb0 = *(const bf16x8*)(Vtb + (size_t)( 0 + lr)*SEQ + kvc + lg*8);
    bf16x8 vb1 = *(const bf16x8*)(Vtb + (size_t)(16 + lr)*SEQ + kvc + lg*8);
    bf16x8 vb2 = *(const bf16x8*)(Vtb + (size_t)(32 + lr)*SEQ + kvc + lg*8);
    bf16x8 vb3 = *(const bf16x8*)(Vtb + (size_t)(48 + lr)*SEQ + kvc + lg*8);

    const unsigned short* krA  = Khb + (size_t)(kvc + lr)*DIM + lg*8;
    const unsigned short* krlA = Klb + (size_t)(kvc + lr)*DIM + lg*8;
    bf16x8 kh0A = *(const bf16x8*)krA,        kh1A = *(const bf16x8*)(krA + 32);
    bf16x8 kl0A = *(const bf16x8*)krlA,       kl1A = *(const bf16x8*)(krlA + 32);
    bf16x8 kh0B = *(const bf16x8*)(krA  + 16*DIM), kh1B = *(const bf16x8*)(krA  + 16*DIM + 32);
    bf16x8 kl0B = *(const bf16x8*)(krlA + 16*DIM), kl1B = *(const bf16x8*)(krlA + 16*DIM + 32);

    f32x4 aA={0,0,0,0}, bA={0,0,0,0}, aB={0,0,0,0}, bB={0,0,0,0};
    aA = MFMA_BF16(kh0A, qh[0], aA, 0,0,0);
    aA = MFMA_BF16(kh1A, qh[1], aA, 0,0,0);
    bA = MFMA_BF16(kl0A, qh[0], bA, 0,0,0);
    bA = MFMA_BF16(kl1A, qh[1], bA, 0,0,0);
    bA = MFMA_BF16(kh0A, ql[0], bA, 0,0,0);
    bA = MFMA_BF16(kh1A, ql[1], bA, 0,0,0);
    aB = MFMA_BF16(kh0B, qh[0], aB, 0,0,0);
    aB = MFMA_BF16(kh1B, qh[1], aB, 0,0,0);
    bB = MFMA_BF16(kl0B, qh[0], bB, 0,0,0);
    bB = MFMA_BF16(kl1B, qh[1], bB, 0,0,0);
    bB = MFMA_BF16(kh0B, ql[0], bB, 0,0,0);
    bB = MFMA_BF16(kh1B, ql[1], bB, 0,0,0);

    float pA[4], pB[4];
    #pragma unroll
    for (int r=0;r<4;++r){
      pA[r] = __expf(aA[r] + bA[r]) * rv;
      pB[r] = __expf(aB[r] + bB[r]) * rv;
    }
    // stores replaced by keepalives (rule #17: keep upstream chain live)
    asm volatile("" :: "v"(pA[0]), "v"(pA[1]), "v"(pA[2]), "v"(pA[3]));
    asm volatile("" :: "v"(pB[0]), "v"(pB[1]), "v"(pB[2]), "v"(pB[3]));

    unsigned a0, a1, b0, b1;
    asm("v_cvt_pk_bf16_f32 %0, %1, %2" : "=v"(a0) : "v"(pA[0]), "v"(pA[1]));
    asm("v_cvt_pk_bf16_f32 %0, %1, %2" : "=v"(a1) : "v"(pA[2]), "v"(pA[3]));
    asm("v_cvt_pk_bf16_f32 %0, %1, %2" : "=v"(b0) : "v"(pB[0]), "v"(pB[1]));
    asm("v_cvt_pk_bf16_f32 %0, %1, %2" : "=v"(b1) : "v"(pB[2]), "v"(pB[3]));
    unsigned t0a = (unsigned)__shfl((int)a0, src0, 64);
    unsigned t1a = (unsigned)__shfl((int)a1, src0, 64);
    unsigned t2a = (unsigned)__shfl((int)a0, src1, 64);
    unsigned t3a = (unsigned)__shfl((int)a1, src1, 64);
    unsigned t0b = (unsigned)__shfl((int)b0, src0, 64);
    unsigned t1b = (unsigned)__shfl((int)b1, src0, 64);
    unsigned t2b = (unsigned)__shfl((int)b0, src1, 64);
    unsigned t3b = (unsigned)__shfl((int)b1, src1, 64);
    union { bf16x8 v; unsigned u[4]; } pu;
    pu.u[0] = losel ? t0a : t0b;
    pu.u[1] = losel ? t1a : t1b;
    pu.u[2] = losel ? t2a : t2b;
    pu.u[3] = losel ? t3a : t3b;
    bf16x8 pa = pu.v;

    o0 = MFMA_BF16(pa, vb0, o0, 0,0,0);
    o1 = MFMA_BF16(pa, vb1, o1, 0,0,0);
    o2 = MFMA_BF16(pa, vb2, o2, 0,0,0);
    o3 = MFMA_BF16(pa, vb3, o3, 0,0,0);
  }

  if (w > 0){
    #pragma unroll
    for (int r=0;r<4;++r){
      int base = (w-1)*1024 + (lg*4 + r)*16 + lr;
      ctile[base +   0] = o0[r];
      ctile[base + 256] = o1[r];
      ctile[base + 512] = o2[r];
      ctile[base + 768] = o3[r];
    }
  }
  __syncthreads();
  if (w == 0){
    #pragma unroll
    for (int r=0;r<4;++r){
      int idx = (lg*4 + r)*16 + lr;
      float v0 = o0[r] + ctile[idx      ] + ctile[1024+idx      ] + ctile[2048+idx      ];
      float v1 = o1[r] + ctile[idx + 256] + ctile[1024+idx + 256] + ctile[2048+idx + 256];
      float v2 = o2[r] + ctile[idx + 512] + ctile[1024+idx + 512] + ctile[2048+idx + 512];
      float v3 = o3[r] + ctile[idx + 768] + ctile[1024+idx + 768] + ctile[2048+idx + 768];
      asm volatile("" :: "v"(v0), "v"(v1), "v"(v2), "v"(v3));
    }
  }
}

// ---------------- real fused attention (identical to R6) ----------------
__global__ __launch_bounds__(256, 4) void attn_fused(
    const float* __restrict__ Q,
    const unsigned short* __restrict__ Khi,
    const unsigned short* __restrict__ Klo,
    const unsigned short* __restrict__ Vt,
    float* __restrict__ ctx_out,
    float* __restrict__ attn_out){

  __shared__ float red[64];
  __shared__ float ctile[3072];

  int tid = threadIdx.x;
  int w = tid >> 6, l = tid & 63;
  int lr = l & 15, lg = l >> 4;

  int bid = blockIdx.x;
  int swz = (bid & 7)*(NTILE/8) + (bid >> 3);
  int bh = swz >> 7;
  int q0 = (swz & 127) << 4;
  size_t bhq = (size_t)bh*SEQ;

  bf16x8 qh[2], ql[2];
  load_q_hilo(Q + (bhq + q0 + lr)*DIM + lg*8, qh, ql);

  const unsigned short* Khb = Khi + bhq*DIM;
  const unsigned short* Klb = Klo + bhq*DIM;
  const unsigned short* Vtb = Vt  + bhq*DIM;
  const int kvbase = w*512;

  float rs = 0.f;
  #pragma unroll 2
  for (int t=0; t<16; ++t){
    int kv0 = kvbase + t*32;
    const unsigned short* kr = Khb + (size_t)(kv0 + lr)*DIM + lg*8;
    bf16x8 kh0 = *(const bf16x8*)kr;
    bf16x8 kh1 = *(const bf16x8*)(kr + 32);
    bf16x8 kh0B = *(const bf16x8*)(kr + 16*DIM);
    bf16x8 kh1B = *(const bf16x8*)(kr + 16*DIM + 32);
    f32x4 a = {0,0,0,0}, b = {0,0,0,0};
    a = MFMA_BF16(kh0,  qh[0], a, 0,0,0);
    a = MFMA_BF16(kh1,  qh[1], a, 0,0,0);
    b = MFMA_BF16(kh0B, qh[0], b, 0,0,0);
    b = MFMA_BF16(kh1B, qh[1], b, 0,0,0);
    #pragma unroll
    for (int r=0;r<4;++r) rs += __expf(a[r]) + __expf(b[r]);
  }
  rs += __shfl_xor(rs, 16, 64);
  rs += __shfl_xor(rs, 32, 64);
  if (l < 16) red[w*16 + l] = rs;
  __syncthreads();
  float rv = 1.0f/(red[lr] + red[16+lr] + red[32+lr] + red[48+lr] + 1e-8f);

  float* attn_row = attn_out + (bhq + q0 + lr)*SEQ;
  f32x4 o0={0,0,0,0}, o1={0,0,0,0}, o2={0,0,0,0}, o3={0,0,0,0};
  int src0 = lr + ((lg & 1) ? 32 : 0);
  int src1 = src0 + 16;
  bool losel = (lg < 2);

  for (int c=0; c<16; ++c){
    int kvc = kvbase + c*32;

    bf16x8 vb0 = *(const bf16x8*)(Vtb + (size_t)( 0 + lr)*SEQ + kvc + lg*8);
    bf16x8 vb1 = *(const bf16x8*)(Vtb + (size_t)(16 + lr)*SEQ + kvc + lg*8);
    bf16x8 vb2 = *(const bf16x8*)(Vtb + (size_t)(32 + lr)*SEQ + kvc + lg*8);
    bf16x8 vb3 = *(const bf16x8*)(Vtb + (size_t)(48 + lr)*SEQ + kvc + lg*8);

    const unsigned short* krA  = Khb + (size_t)(kvc + lr)*DIM + lg*8;
    const unsigned short* krlA = Klb + (size_t)(kvc + lr)*DIM + lg*8;
    bf16x8 kh0A = *(const bf16x8*)krA,        kh1A = *(const bf16x8*)(krA + 32);
    bf16x8 kl0A = *(const bf16x8*)krlA,       kl1A = *(const bf16x8*)(krlA + 32);
    bf16x8 kh0B = *(const bf16x8*)(krA  + 16*DIM), kh1B = *(const bf16x8*)(krA  + 16*DIM + 32);
    bf16x8 kl0B = *(const bf16x8*)(krlA + 16*DIM), kl1B = *(const bf16x8*)(krlA + 16*DIM + 32);

    f32x4 aA={0,0,0,0}, bA={0,0,0,0}, aB={0,0,0,0}, bB={0,0,0,0};
    aA = MFMA_BF16(kh0A, qh[0], aA, 0,0,0);
    aA = MFMA_BF16(kh1A, qh[1], aA, 0,0,0);
    bA = MFMA_BF16(kl0A, qh[0], bA, 0,0,0);
    bA = MFMA_BF16(kl1A, qh[1], bA, 0,0,0);
    bA = MFMA_BF16(kh0A, ql[0], bA, 0,0,0);
    bA = MFMA_BF16(kh1A, ql[1], bA, 0,0,0);
    aB = MFMA_BF16(kh0B, qh[0], aB, 0,0,0);
    aB = MFMA_BF16(kh1B, qh[1], aB, 0,0,0);
    bB = MFMA_BF16(kl0B, qh[0], bB, 0,0,0);
    bB = MFMA_BF16(kl1B, qh[1], bB, 0,0,0);
    bB = MFMA_BF16(kh0B, ql[0], bB, 0,0,0);
    bB = MFMA_BF16(kh1B, ql[1], bB, 0,0,0);

    float pA[4], pB[4];
    #pragma unroll
    for (int r=0;r<4;++r){
      pA[r] = __expf(aA[r] + bA[r]) * rv;
      pB[r] = __expf(aB[r] + bB[r]) * rv;
    }
    f32x4 stA = {pA[0], pA[1], pA[2], pA[3]};
    f32x4 stB = {pB[0], pB[1], pB[2], pB[3]};
    __builtin_nontemporal_store(stA, (f32x4*)(attn_row + kvc + 4*lg));
    __builtin_nontemporal_store(stB, (f32x4*)(attn_row + kvc + 16 + 4*lg));

    unsigned a0, a1, b0, b1;
    asm("v_cvt_pk_bf16_f32 %0, %1, %2" : "=v"(a0) : "v"(pA[0]), "v"(pA[1]));
    asm("v_cvt_pk_bf16_f32 %0, %1, %2" : "=v"(a1) : "v"(pA[2]), "v"(pA[3]));
    asm("v_cvt_pk_bf16_f32 %0, %1, %2" : "=v"(b0) : "v"(pB[0]), "v"(pB[1]));
    asm("v_cvt_pk_bf16_f32 %0, %1, %2" : "=v"(b1) : "v"(pB[2]), "v"(pB[3]));
    unsigned t0a = (unsigned)__shfl((int)a0, src0, 64);
    unsigned t1a = (unsigned)__shfl((int)a1, src0, 64);
    unsigned t2a = (unsigned)__shfl((int)a0, src1, 64);
    unsigned t3a = (unsigned)__shfl((int)a1, src1, 64);
    unsigned t0b = (unsigned)__shfl((int)b0, src0, 64);
    unsigned t1b = (unsigned)__shfl((int)b1, src0, 64);
    unsigned t2b = (unsigned)__shfl((int)b0, src1, 64);
    unsigned t3b = (unsigned)__shfl((int)b1, src1, 64);
    union { bf16x8 v; unsigned u[4]; } pu;
    pu.u[0] = losel ? t0a : t0b;
    pu.u[1] = losel ? t1a : t1b;
    pu.u[2] = losel ? t2a : t2b;
    pu.u[3] = losel ? t3a : t3b;
    bf16x8 pa = pu.v;

    o0 = MFMA_BF16(pa, vb0, o0, 0,0,0);
    o1 = MFMA_BF16(pa, vb1, o1, 0,0,0);
    o2 = MFMA_BF16(pa, vb2, o2, 0,0,0);
    o3 = MFMA_BF16(pa, vb3, o3, 0,0,0);
  }

  if (w > 0){
    #pragma unroll
    for (int r=0;r<4;++r){
      int base = (w-1)*1024 + (lg*4 + r)*16 + lr;
      ctile[base +   0] = o0[r];
      ctile[base + 256] = o1[r];
      ctile[base + 512] = o2[r];
      ctile[base + 768] = o3[r];
    }
  }
  __syncthreads();
  if (w == 0){
    #pragma unroll
    for (int r=0;r<4;++r){
      int idx = (lg*4 + r)*16 + lr;
      float v0 = o0[r] + ctile[idx      ] + ctile[1024+idx      ] + ctile[2048+idx      ];
      float v1 = o1[r] + ctile[idx + 256] + ctile[1024+idx + 256] + ctile[2048+idx + 256];
      float v2 = o2[r] + ctile[idx + 512] + ctile[1024+idx + 512] + ctile[2048+idx + 512];
      float v3 = o3[r] + ctile[idx + 768] + ctile[1024+idx + 768] + ctile[2048+idx + 768];
      size_t rowoff = (bhq + q0 + lg*4 + r)*DIM + lr;
      __builtin_nontemporal_store(v0, ctx_out + rowoff +  0);
      __builtin_nontemporal_store(v1, ctx_out + rowoff + 16);
      __builtin_nontemporal_store(v2, ctx_out + rowoff + 32);
      __builtin_nontemporal_store(v3, ctx_out + rowoff + 48);
    }
  }
}

extern "C" void kernel_launch(void* const* d_in, const int* in_sizes, int n_in,
                              void* d_out, int out_size, void* d_ws, size_t ws_size,
                              hipStream_t stream) {
  const float* Q = (const float*)d_in[0];
  const float* K = (const float*)d_in[1];
  const float* V = (const float*)d_in[2];
  float* ctx_out  = (float*)d_out;
  float* attn_out = ctx_out + (size_t)NELEM;

  unsigned short* Khi = (unsigned short*)d_ws;
  unsigned short* Klo = Khi + (size_t)NELEM;
  unsigned short* Vt  = Klo + (size_t)NELEM;

  // prep (probes 3 needs Khi/Klo/Vt)
  prep_split_k<<<1024, 256, 0, stream>>>(K, Khi, Klo);
  prep_transpose_v<<<BH*32, 256, 0, stream>>>(V, Vt);

  // ---- probes (write garbage into d_out attn region; real kernel rewrites all) ----
  probe_store_linear<<<4096, 256, 0, stream>>>(attn_out);
  probe_store_pattern<<<NTILE, 256, 0, stream>>>(attn_out);
  probe_compute_nostore<<<NTILE, 256, 0, stream>>>(Q, Khi, Klo, Vt);

  // ---- real kernel last: produces the validated output ----
  attn_fused<<<NTILE, 256, 0, stream>>>(Q, Khi, Klo, Vt, ctx_out, attn_out);
}

// Round 8
// 994.659 us; speedup vs baseline: 1.8495x; 1.8495x over previous
//
#include <hip/hip_runtime.h>
#include <stdint.h>

#define SEQ   2048
#define DIM   64
#define BH    48
#define NELEM (BH*SEQ*DIM)          // 6291456
#define NTILE (BH*(SEQ/16))         // 6144 q-tiles

typedef __attribute__((ext_vector_type(4))) float f32x4;
typedef __attribute__((ext_vector_type(8))) short bf16x8;

#define MFMA_BF16 __builtin_amdgcn_mfma_f32_16x16x32_bf16

static __device__ __forceinline__ unsigned short f2bf(float x){
  unsigned int u = __float_as_uint(x);
  u += 0x7fffu + ((u >> 16) & 1u);
  return (unsigned short)(u >> 16);
}
static __device__ __forceinline__ float bf2f(unsigned int h){
  return __uint_as_float(h << 16);
}

// ---------------- prep: K -> (Khi, Klo) bf16 split ----------------
__global__ void prep_split_k(const float* __restrict__ K,
                             unsigned short* __restrict__ Khi,
                             unsigned short* __restrict__ Klo){
  const int n4 = NELEM/4;
  for (int i = blockIdx.x*blockDim.x + threadIdx.x; i < n4; i += gridDim.x*blockDim.x){
    float4 k = ((const float4*)K)[i];
    float kv[4] = {k.x,k.y,k.z,k.w};
    unsigned short h[4], lo[4];
    #pragma unroll
    for (int j=0;j<4;++j){
      h[j]  = f2bf(kv[j]);
      lo[j] = f2bf(kv[j] - bf2f(h[j]));
    }
    uint2 hp, lp;
    hp.x = (unsigned)h[0]  | ((unsigned)h[1]<<16);
    hp.y = (unsigned)h[2]  | ((unsigned)h[3]<<16);
    lp.x = (unsigned)lo[0] | ((unsigned)lo[1]<<16);
    lp.y = (unsigned)lo[2] | ((unsigned)lo[3]<<16);
    ((uint2*)Khi)[i] = hp;
    ((uint2*)Klo)[i] = lp;
  }
}

// ---------------- prep: V -> Vt bf16 transposed [bh][d][s] ----------------
__global__ void prep_transpose_v(const float* __restrict__ V,
                                 unsigned short* __restrict__ Vt){
  __shared__ float tile[64][65];
  int bh = blockIdx.x >> 5;
  int s0 = (blockIdx.x & 31) << 6;
  int t  = threadIdx.x;
  const float* Vb = V + ((size_t)bh*SEQ + s0)*DIM;
  #pragma unroll
  for (int r=0;r<4;++r){
    int f = r*1024 + t*4;
    int s = f >> 6, d = f & 63;
    float4 v = *(const float4*)(Vb + f);
    tile[s][d+0]=v.x; tile[s][d+1]=v.y; tile[s][d+2]=v.z; tile[s][d+3]=v.w;
  }
  __syncthreads();
  int d = t >> 2, si = (t & 3) << 4;
  unsigned int o[8];
  #pragma unroll
  for (int u=0;u<8;++u){
    unsigned short a = f2bf(tile[si+2*u  ][d]);
    unsigned short b = f2bf(tile[si+2*u+1][d]);
    o[u] = (unsigned)a | ((unsigned)b<<16);
  }
  unsigned short* orow = Vt + (size_t)bh*DIM*SEQ + (size_t)d*SEQ + s0 + si;
  uint4 p0 = make_uint4(o[0],o[1],o[2],o[3]);
  uint4 p1 = make_uint4(o[4],o[5],o[6],o[7]);
  ((uint4*)orow)[0] = p0;
  ((uint4*)orow)[1] = p1;
}

// Q fragment loader (B-operand layout)
static __device__ __forceinline__ void load_q_hilo(const float* Qrow, bf16x8* qh, bf16x8* ql){
  #pragma unroll
  for (int ks=0; ks<2; ++ks){
    float4 a = *(const float4*)(Qrow + ks*32);
    float4 b = *(const float4*)(Qrow + ks*32 + 4);
    float x[8] = {a.x,a.y,a.z,a.w,b.x,b.y,b.z,b.w};
    #pragma unroll
    for (int j=0;j<8;++j){
      float v = x[j]*0.125f;
      unsigned short h = f2bf(v);
      qh[ks][j] = (short)h;
      ql[ks][j] = (short)f2bf(v - bf2f(h));
    }
  }
}

// ======= PROBE: exact attn-store addressing of phase C, no compute, 805 MB ======
__global__ __launch_bounds__(256, 4) void probe_pattern(float* __restrict__ attn_out){
  int tid = threadIdx.x;
  int w = tid >> 6, l = tid & 63;
  int lr = l & 15, lg = l >> 4;
  int bid = blockIdx.x;
  int swz = (bid & 7)*(NTILE/8) + (bid >> 3);
  int bh = swz >> 7;
  int q0 = (swz & 127) << 4;
  size_t bhq = (size_t)bh*SEQ;
  float* attn_row = attn_out + (bhq + q0 + lr)*SEQ;
  int kvbase = w*512;
  f32x4 v = {1.f, 1.f, 1.f, 1.f};
  for (int c=0; c<16; ++c){
    int kvc = kvbase + c*32;
    __builtin_nontemporal_store(v, (f32x4*)(attn_row + kvc + 8*lg));
    __builtin_nontemporal_store(v, (f32x4*)(attn_row + kvc + 8*lg + 4));
  }
}

// ---------------- fused attention: stores fully deferred past all loads ----------------
// LDS P tile: [row 16][kv 2048] bf16, byte addr = row*4096 + kv*2, XOR-swizzled ^((row&3)<<5)
__global__ __launch_bounds__(256, 2) void attn_fused(
    const float* __restrict__ Q,
    const unsigned short* __restrict__ Khi,
    const unsigned short* __restrict__ Klo,
    const unsigned short* __restrict__ Vt,
    float* __restrict__ ctx_out,
    float* __restrict__ attn_out){

  __shared__ unsigned short paL[16*2048];   // 64 KB
  __shared__ float red[64];
  __shared__ float ctile[3072];             // 12 KB

  char* pab = (char*)paL;
  int tid = threadIdx.x;
  int w = tid >> 6, l = tid & 63;
  int lr = l & 15, lg = l >> 4;

  int bid = blockIdx.x;
  int swz = (bid & 7)*(NTILE/8) + (bid >> 3);
  int bh = swz >> 7;
  int q0 = (swz & 127) << 4;
  size_t bhq = (size_t)bh*SEQ;

  bf16x8 qh[2], ql[2];
  load_q_hilo(Q + (bhq + q0 + lr)*DIM + lg*8, qh, ql);

  const unsigned short* Khb = Khi + bhq*DIM;
  const unsigned short* Klb = Klo + bhq*DIM;
  const unsigned short* Vtb = Vt  + bhq*DIM;
  const int kvbase = w*512;
  const int swzb = (lr & 3) << 5;

  // ---- phase B: exact scores (hi/lo), exp UNNORMALIZED, rowsum, P->LDS ----
  float rs = 0.f;
  for (int c=0; c<16; ++c){
    int kvc = kvbase + c*32;
    const unsigned short* krA  = Khb + (size_t)(kvc + lr)*DIM + lg*8;
    const unsigned short* krlA = Klb + (size_t)(kvc + lr)*DIM + lg*8;
    bf16x8 kh0A = *(const bf16x8*)krA,        kh1A = *(const bf16x8*)(krA + 32);
    bf16x8 kl0A = *(const bf16x8*)krlA,       kl1A = *(const bf16x8*)(krlA + 32);
    bf16x8 kh0B = *(const bf16x8*)(krA  + 16*DIM), kh1B = *(const bf16x8*)(krA  + 16*DIM + 32);
    bf16x8 kl0B = *(const bf16x8*)(krlA + 16*DIM), kl1B = *(const bf16x8*)(krlA + 16*DIM + 32);

    f32x4 aA={0,0,0,0}, bA={0,0,0,0}, aB={0,0,0,0}, bB={0,0,0,0};
    aA = MFMA_BF16(kh0A, qh[0], aA, 0,0,0);
    aA = MFMA_BF16(kh1A, qh[1], aA, 0,0,0);
    bA = MFMA_BF16(kl0A, qh[0], bA, 0,0,0);
    bA = MFMA_BF16(kl1A, qh[1], bA, 0,0,0);
    bA = MFMA_BF16(kh0A, ql[0], bA, 0,0,0);
    bA = MFMA_BF16(kh1A, ql[1], bA, 0,0,0);
    aB = MFMA_BF16(kh0B, qh[0], aB, 0,0,0);
    aB = MFMA_BF16(kh1B, qh[1], aB, 0,0,0);
    bB = MFMA_BF16(kl0B, qh[0], bB, 0,0,0);
    bB = MFMA_BF16(kl1B, qh[1], bB, 0,0,0);
    bB = MFMA_BF16(kh0B, ql[0], bB, 0,0,0);
    bB = MFMA_BF16(kh1B, ql[1], bB, 0,0,0);

    float pA[4], pB[4];
    #pragma unroll
    for (int r=0;r<4;++r){
      pA[r] = __expf(aA[r] + bA[r]);      // P[lr][kvc+4lg+r]
      pB[r] = __expf(aB[r] + bB[r]);      // P[lr][kvc+16+4lg+r]
      rs += pA[r] + pB[r];
    }
    unsigned a0, a1, b0, b1;
    asm("v_cvt_pk_bf16_f32 %0, %1, %2" : "=v"(a0) : "v"(pA[0]), "v"(pA[1]));
    asm("v_cvt_pk_bf16_f32 %0, %1, %2" : "=v"(a1) : "v"(pA[2]), "v"(pA[3]));
    asm("v_cvt_pk_bf16_f32 %0, %1, %2" : "=v"(b0) : "v"(pB[0]), "v"(pB[1]));
    asm("v_cvt_pk_bf16_f32 %0, %1, %2" : "=v"(b1) : "v"(pB[2]), "v"(pB[3]));
    int bAaddr = (lr*4096 + (kvc +      4*lg)*2) ^ swzb;
    int bBaddr = (lr*4096 + (kvc + 16 + 4*lg)*2) ^ swzb;
    uint2 wa = {a0, a1}, wb = {b0, b1};
    *(uint2*)(pab + bAaddr) = wa;
    *(uint2*)(pab + bBaddr) = wb;
  }

  // ---- rowsum reduce across lg, then across waves ----
  rs += __shfl_xor(rs, 16, 64);
  rs += __shfl_xor(rs, 32, 64);
  if (l < 16) red[w*16 + l] = rs;
  __syncthreads();
  float rv = 1.0f/(red[lr] + red[16+lr] + red[32+lr] + red[48+lr] + 1e-8f);

  // ---- phase D: PV (pure loads+MFMA, no stores in flight) ----
  f32x4 o0={0,0,0,0}, o1={0,0,0,0}, o2={0,0,0,0}, o3={0,0,0,0};
  for (int c=0; c<16; ++c){
    int kvc = kvbase + c*32;
    int bR = (lr*4096 + (kvc + 8*lg)*2) ^ swzb;
    bf16x8 pa = *(const bf16x8*)(pab + bR);   // A-frag: row lr, k=8lg+j
    bf16x8 vb0 = *(const bf16x8*)(Vtb + (size_t)( 0 + lr)*SEQ + kvc + lg*8);
    bf16x8 vb1 = *(const bf16x8*)(Vtb + (size_t)(16 + lr)*SEQ + kvc + lg*8);
    bf16x8 vb2 = *(const bf16x8*)(Vtb + (size_t)(32 + lr)*SEQ + kvc + lg*8);
    bf16x8 vb3 = *(const bf16x8*)(Vtb + (size_t)(48 + lr)*SEQ + kvc + lg*8);
    o0 = MFMA_BF16(pa, vb0, o0, 0,0,0);
    o1 = MFMA_BF16(pa, vb1, o1, 0,0,0);
    o2 = MFMA_BF16(pa, vb2, o2, 0,0,0);
    o3 = MFMA_BF16(pa, vb3, o3, 0,0,0);
  }

  // per-row inverse sums for ctx rows 4lg+r
  float rvD[4];
  #pragma unroll
  for (int r=0;r<4;++r){
    int row = lg*4 + r;
    rvD[r] = 1.0f/(red[row] + red[16+row] + red[32+row] + red[48+row] + 1e-8f);
  }

  // ---- ctx cross-wave reduce + stores (unnormalized accum, scale at end) ----
  if (w > 0){
    #pragma unroll
    for (int r=0;r<4;++r){
      int base = (w-1)*1024 + (lg*4 + r)*16 + lr;
      ctile[base +   0] = o0[r];
      ctile[base + 256] = o1[r];
      ctile[base + 512] = o2[r];
      ctile[base + 768] = o3[r];
    }
  }
  __syncthreads();
  if (w == 0){
    #pragma unroll
    for (int r=0;r<4;++r){
      int idx = (lg*4 + r)*16 + lr;
      float v0 = (o0[r] + ctile[idx      ] + ctile[1024+idx      ] + ctile[2048+idx      ])*rvD[r];
      float v1 = (o1[r] + ctile[idx + 256] + ctile[1024+idx + 256] + ctile[2048+idx + 256])*rvD[r];
      float v2 = (o2[r] + ctile[idx + 512] + ctile[1024+idx + 512] + ctile[2048+idx + 512])*rvD[r];
      float v3 = (o3[r] + ctile[idx + 768] + ctile[1024+idx + 768] + ctile[2048+idx + 768])*rvD[r];
      size_t rowoff = (bhq + q0 + lg*4 + r)*DIM + lr;
      __builtin_nontemporal_store(v0, ctx_out + rowoff +  0);
      __builtin_nontemporal_store(v1, ctx_out + rowoff + 16);
      __builtin_nontemporal_store(v2, ctx_out + rowoff + 32);
      __builtin_nontemporal_store(v3, ctx_out + rowoff + 48);
    }
  }

  // ---- phase C (LAST): attn write — pure store stream, nothing waits on it ----
  {
    float* attn_row = attn_out + (bhq + q0 + lr)*SEQ;
    for (int c=0; c<16; ++c){
      int kvc = kvbase + c*32;
      int bR = (lr*4096 + (kvc + 8*lg)*2) ^ swzb;
      bf16x8 pv = *(const bf16x8*)(pab + bR);
      f32x4 s0, s1;
      #pragma unroll
      for (int j=0;j<4;++j) s0[j] = bf2f((unsigned short)pv[j]) * rv;
      #pragma unroll
      for (int j=0;j<4;++j) s1[j] = bf2f((unsigned short)pv[4+j]) * rv;
      __builtin_nontemporal_store(s0, (f32x4*)(attn_row + kvc + 8*lg));
      __builtin_nontemporal_store(s1, (f32x4*)(attn_row + kvc + 8*lg + 4));
    }
  }
}

extern "C" void kernel_launch(void* const* d_in, const int* in_sizes, int n_in,
                              void* d_out, int out_size, void* d_ws, size_t ws_size,
                              hipStream_t stream) {
  const float* Q = (const float*)d_in[0];
  const float* K = (const float*)d_in[1];
  const float* V = (const float*)d_in[2];
  float* ctx_out  = (float*)d_out;
  float* attn_out = ctx_out + (size_t)NELEM;

  unsigned short* Khi = (unsigned short*)d_ws;
  unsigned short* Klo = Khi + (size_t)NELEM;
  unsigned short* Vt  = Klo + (size_t)NELEM;

  prep_split_k<<<1024, 256, 0, stream>>>(K, Khi, Klo);
  prep_transpose_v<<<BH*32, 256, 0, stream>>>(V, Vt);

  // probe first (garbage into attn region; main kernel rewrites everything)
  probe_pattern<<<NTILE, 256, 0, stream>>>(attn_out);

  attn_fused<<<NTILE, 256, 0, stream>>>(Q, Khi, Klo, Vt, ctx_out, attn_out);
}

// Round 9
// 620.071 us; speedup vs baseline: 2.9667x; 1.6041x over previous
//
#include <hip/hip_runtime.h>
#include <stdint.h>

#define SEQ   2048
#define DIM   64
#define BH    48
#define NELEM (BH*SEQ*DIM)          // 6291456
#define NTILE (BH*(SEQ/16))         // 6144 q-tiles

typedef __attribute__((ext_vector_type(4))) float f32x4;
typedef __attribute__((ext_vector_type(8))) short bf16x8;

#define MFMA_BF16 __builtin_amdgcn_mfma_f32_16x16x32_bf16

static __device__ __forceinline__ unsigned short f2bf(float x){
  unsigned int u = __float_as_uint(x);
  u += 0x7fffu + ((u >> 16) & 1u);
  return (unsigned short)(u >> 16);
}
static __device__ __forceinline__ float bf2f(unsigned int h){
  return __uint_as_float(h << 16);
}

// ---------------- prep: K -> (Khi, Klo) bf16 split ----------------
__global__ void prep_split_k(const float* __restrict__ K,
                             unsigned short* __restrict__ Khi,
                             unsigned short* __restrict__ Klo){
  const int n4 = NELEM/4;
  for (int i = blockIdx.x*blockDim.x + threadIdx.x; i < n4; i += gridDim.x*blockDim.x){
    float4 k = ((const float4*)K)[i];
    float kv[4] = {k.x,k.y,k.z,k.w};
    unsigned short h[4], lo[4];
    #pragma unroll
    for (int j=0;j<4;++j){
      h[j]  = f2bf(kv[j]);
      lo[j] = f2bf(kv[j] - bf2f(h[j]));
    }
    uint2 hp, lp;
    hp.x = (unsigned)h[0]  | ((unsigned)h[1]<<16);
    hp.y = (unsigned)h[2]  | ((unsigned)h[3]<<16);
    lp.x = (unsigned)lo[0] | ((unsigned)lo[1]<<16);
    lp.y = (unsigned)lo[2] | ((unsigned)lo[3]<<16);
    ((uint2*)Khi)[i] = hp;
    ((uint2*)Klo)[i] = lp;
  }
}

// ---------------- prep: V -> Vt bf16 transposed [bh][d][s] ----------------
__global__ void prep_transpose_v(const float* __restrict__ V,
                                 unsigned short* __restrict__ Vt){
  __shared__ float tile[64][65];
  int bh = blockIdx.x >> 5;
  int s0 = (blockIdx.x & 31) << 6;
  int t  = threadIdx.x;
  const float* Vb = V + ((size_t)bh*SEQ + s0)*DIM;
  #pragma unroll
  for (int r=0;r<4;++r){
    int f = r*1024 + t*4;
    int s = f >> 6, d = f & 63;
    float4 v = *(const float4*)(Vb + f);
    tile[s][d+0]=v.x; tile[s][d+1]=v.y; tile[s][d+2]=v.z; tile[s][d+3]=v.w;
  }
  __syncthreads();
  int d = t >> 2, si = (t & 3) << 4;
  unsigned int o[8];
  #pragma unroll
  for (int u=0;u<8;++u){
    unsigned short a = f2bf(tile[si+2*u  ][d]);
    unsigned short b = f2bf(tile[si+2*u+1][d]);
    o[u] = (unsigned)a | ((unsigned)b<<16);
  }
  unsigned short* orow = Vt + (size_t)bh*DIM*SEQ + (size_t)d*SEQ + s0 + si;
  uint4 p0 = make_uint4(o[0],o[1],o[2],o[3]);
  uint4 p1 = make_uint4(o[4],o[5],o[6],o[7]);
  ((uint4*)orow)[0] = p0;
  ((uint4*)orow)[1] = p1;
}

// Q fragment loader (B-operand layout)
static __device__ __forceinline__ void load_q_hilo(const float* Qrow, bf16x8* qh, bf16x8* ql){
  #pragma unroll
  for (int ks=0; ks<2; ++ks){
    float4 a = *(const float4*)(Qrow + ks*32);
    float4 b = *(const float4*)(Qrow + ks*32 + 4);
    float x[8] = {a.x,a.y,a.z,a.w,b.x,b.y,b.z,b.w};
    #pragma unroll
    for (int j=0;j<8;++j){
      float v = x[j]*0.125f;
      unsigned short h = f2bf(v);
      qh[ks][j] = (short)h;
      ql[ks][j] = (short)f2bf(v - bf2f(h));
    }
  }
}

// ---------------- fused attention: P in REGISTERS, stores fully deferred ----------------
__global__ __launch_bounds__(256, 2) void attn_fused(
    const float* __restrict__ Q,
    const unsigned short* __restrict__ Khi,
    const unsigned short* __restrict__ Klo,
    const unsigned short* __restrict__ Vt,
    float* __restrict__ ctx_out,
    float* __restrict__ attn_out){

  __shared__ float red[64];          // 4 waves x 16 rows
  __shared__ float ctile[3072];      // 12 KB: 3 waves x 4 d-tiles x 16x16

  int tid = threadIdx.x;
  int w = tid >> 6, l = tid & 63;
  int lr = l & 15, lg = l >> 4;

  // XCD-aware bijective swizzle (6144 % 8 == 0)
  int bid = blockIdx.x;
  int swz = (bid & 7)*(NTILE/8) + (bid >> 3);
  int bh = swz >> 7;
  int q0 = (swz & 127) << 4;
  size_t bhq = (size_t)bh*SEQ;

  bf16x8 qh[2], ql[2];
  load_q_hilo(Q + (bhq + q0 + lr)*DIM + lg*8, qh, ql);

  const unsigned short* Khb = Khi + bhq*DIM;
  const unsigned short* Klb = Klo + bhq*DIM;
  const unsigned short* Vtb = Vt  + bhq*DIM;
  const int kvbase = w*512;

  // P tile in registers: 64 packed-bf16 uints (unnormalized exp scores)
  unsigned pA0[16], pA1[16], pB0[16], pB1[16];

  // ---- phase B: exact scores (hi/lo), exp UNNORMALIZED, rowsum, pack->regs ----
  float rs = 0.f;
  #pragma unroll
  for (int c=0; c<16; ++c){
    int kvc = kvbase + c*32;
    const unsigned short* krA  = Khb + (size_t)(kvc + lr)*DIM + lg*8;
    const unsigned short* krlA = Klb + (size_t)(kvc + lr)*DIM + lg*8;
    bf16x8 kh0A = *(const bf16x8*)krA,        kh1A = *(const bf16x8*)(krA + 32);
    bf16x8 kl0A = *(const bf16x8*)krlA,       kl1A = *(const bf16x8*)(krlA + 32);
    bf16x8 kh0B = *(const bf16x8*)(krA  + 16*DIM), kh1B = *(const bf16x8*)(krA  + 16*DIM + 32);
    bf16x8 kl0B = *(const bf16x8*)(krlA + 16*DIM), kl1B = *(const bf16x8*)(krlA + 16*DIM + 32);

    f32x4 aA={0,0,0,0}, bA={0,0,0,0}, aB={0,0,0,0}, bB={0,0,0,0};
    aA = MFMA_BF16(kh0A, qh[0], aA, 0,0,0);
    aA = MFMA_BF16(kh1A, qh[1], aA, 0,0,0);
    bA = MFMA_BF16(kl0A, qh[0], bA, 0,0,0);
    bA = MFMA_BF16(kl1A, qh[1], bA, 0,0,0);
    bA = MFMA_BF16(kh0A, ql[0], bA, 0,0,0);
    bA = MFMA_BF16(kh1A, ql[1], bA, 0,0,0);
    aB = MFMA_BF16(kh0B, qh[0], aB, 0,0,0);
    aB = MFMA_BF16(kh1B, qh[1], aB, 0,0,0);
    bB = MFMA_BF16(kl0B, qh[0], bB, 0,0,0);
    bB = MFMA_BF16(kl1B, qh[1], bB, 0,0,0);
    bB = MFMA_BF16(kh0B, ql[0], bB, 0,0,0);
    bB = MFMA_BF16(kh1B, ql[1], bB, 0,0,0);

    float pA[4], pB[4];
    #pragma unroll
    for (int r=0;r<4;++r){
      pA[r] = __expf(aA[r] + bA[r]);      // P[lr][kvc+4lg+r]
      pB[r] = __expf(aB[r] + bB[r]);      // P[lr][kvc+16+4lg+r]
      rs += pA[r] + pB[r];
    }
    unsigned a0, a1, b0, b1;
    asm("v_cvt_pk_bf16_f32 %0, %1, %2" : "=v"(a0) : "v"(pA[0]), "v"(pA[1]));
    asm("v_cvt_pk_bf16_f32 %0, %1, %2" : "=v"(a1) : "v"(pA[2]), "v"(pA[3]));
    asm("v_cvt_pk_bf16_f32 %0, %1, %2" : "=v"(b0) : "v"(pB[0]), "v"(pB[1]));
    asm("v_cvt_pk_bf16_f32 %0, %1, %2" : "=v"(b1) : "v"(pB[2]), "v"(pB[3]));
    pA0[c] = a0; pA1[c] = a1; pB0[c] = b0; pB1[c] = b1;
  }

  // ---- rowsum reduce across lg, then across waves ----
  rs += __shfl_xor(rs, 16, 64);
  rs += __shfl_xor(rs, 32, 64);
  if (l < 16) red[w*16 + l] = rs;
  __syncthreads();
  float rv = 1.0f/(red[lr] + red[16+lr] + red[32+lr] + red[48+lr] + 1e-8f);

  // ---- phase D: PV (shfl-redistribute P from regs, loads+MFMA, no stores) ----
  f32x4 o0={0,0,0,0}, o1={0,0,0,0}, o2={0,0,0,0}, o3={0,0,0,0};
  int src0 = lr + ((lg & 1) ? 32 : 0);
  int src1 = src0 + 16;
  bool losel = (lg < 2);
  #pragma unroll
  for (int c=0; c<16; ++c){
    int kvc = kvbase + c*32;
    unsigned t0a = (unsigned)__shfl((int)pA0[c], src0, 64);
    unsigned t1a = (unsigned)__shfl((int)pA1[c], src0, 64);
    unsigned t2a = (unsigned)__shfl((int)pA0[c], src1, 64);
    unsigned t3a = (unsigned)__shfl((int)pA1[c], src1, 64);
    unsigned t0b = (unsigned)__shfl((int)pB0[c], src0, 64);
    unsigned t1b = (unsigned)__shfl((int)pB1[c], src0, 64);
    unsigned t2b = (unsigned)__shfl((int)pB0[c], src1, 64);
    unsigned t3b = (unsigned)__shfl((int)pB1[c], src1, 64);
    union { bf16x8 v; unsigned u[4]; } pu;
    pu.u[0] = losel ? t0a : t0b;
    pu.u[1] = losel ? t1a : t1b;
    pu.u[2] = losel ? t2a : t2b;
    pu.u[3] = losel ? t3a : t3b;
    bf16x8 pa = pu.v;

    bf16x8 vb0 = *(const bf16x8*)(Vtb + (size_t)( 0 + lr)*SEQ + kvc + lg*8);
    bf16x8 vb1 = *(const bf16x8*)(Vtb + (size_t)(16 + lr)*SEQ + kvc + lg*8);
    bf16x8 vb2 = *(const bf16x8*)(Vtb + (size_t)(32 + lr)*SEQ + kvc + lg*8);
    bf16x8 vb3 = *(const bf16x8*)(Vtb + (size_t)(48 + lr)*SEQ + kvc + lg*8);
    o0 = MFMA_BF16(pa, vb0, o0, 0,0,0);
    o1 = MFMA_BF16(pa, vb1, o1, 0,0,0);
    o2 = MFMA_BF16(pa, vb2, o2, 0,0,0);
    o3 = MFMA_BF16(pa, vb3, o3, 0,0,0);
  }

  // per-row inverse sums for ctx rows 4lg+r
  float rvD[4];
  #pragma unroll
  for (int r=0;r<4;++r){
    int row = lg*4 + r;
    rvD[r] = 1.0f/(red[row] + red[16+row] + red[32+row] + red[48+row] + 1e-8f);
  }

  // ---- ctx cross-wave reduce + stores ----
  if (w > 0){
    #pragma unroll
    for (int r=0;r<4;++r){
      int base = (w-1)*1024 + (lg*4 + r)*16 + lr;
      ctile[base +   0] = o0[r];
      ctile[base + 256] = o1[r];
      ctile[base + 512] = o2[r];
      ctile[base + 768] = o3[r];
    }
  }
  __syncthreads();
  if (w == 0){
    #pragma unroll
    for (int r=0;r<4;++r){
      int idx = (lg*4 + r)*16 + lr;
      float v0 = (o0[r] + ctile[idx      ] + ctile[1024+idx      ] + ctile[2048+idx      ])*rvD[r];
      float v1 = (o1[r] + ctile[idx + 256] + ctile[1024+idx + 256] + ctile[2048+idx + 256])*rvD[r];
      float v2 = (o2[r] + ctile[idx + 512] + ctile[1024+idx + 512] + ctile[2048+idx + 512])*rvD[r];
      float v3 = (o3[r] + ctile[idx + 768] + ctile[1024+idx + 768] + ctile[2048+idx + 768])*rvD[r];
      size_t rowoff = (bhq + q0 + lg*4 + r)*DIM + lr;
      __builtin_nontemporal_store(v0, ctx_out + rowoff +  0);
      __builtin_nontemporal_store(v1, ctx_out + rowoff + 16);
      __builtin_nontemporal_store(v2, ctx_out + rowoff + 32);
      __builtin_nontemporal_store(v3, ctx_out + rowoff + 48);
    }
  }

  // ---- phase C (LAST): attn write — unpack regs, pure NT store stream ----
  {
    float* attn_row = attn_out + (bhq + q0 + lr)*SEQ;
    #pragma unroll
    for (int c=0; c<16; ++c){
      int kvc = kvbase + c*32;
      f32x4 s0, s1;
      s0[0] = __uint_as_float(pA0[c] << 16) * rv;
      s0[1] = __uint_as_float(pA0[c] & 0xffff0000u) * rv;
      s0[2] = __uint_as_float(pA1[c] << 16) * rv;
      s0[3] = __uint_as_float(pA1[c] & 0xffff0000u) * rv;
      s1[0] = __uint_as_float(pB0[c] << 16) * rv;
      s1[1] = __uint_as_float(pB0[c] & 0xffff0000u) * rv;
      s1[2] = __uint_as_float(pB1[c] << 16) * rv;
      s1[3] = __uint_as_float(pB1[c] & 0xffff0000u) * rv;
      __builtin_nontemporal_store(s0, (f32x4*)(attn_row + kvc + 4*lg));
      __builtin_nontemporal_store(s1, (f32x4*)(attn_row + kvc + 16 + 4*lg));
    }
  }
}

extern "C" void kernel_launch(void* const* d_in, const int* in_sizes, int n_in,
                              void* d_out, int out_size, void* d_ws, size_t ws_size,
                              hipStream_t stream) {
  const float* Q = (const float*)d_in[0];
  const float* K = (const float*)d_in[1];
  const float* V = (const float*)d_in[2];
  float* ctx_out  = (float*)d_out;
  float* attn_out = ctx_out + (size_t)NELEM;

  unsigned short* Khi = (unsigned short*)d_ws;
  unsigned short* Klo = Khi + (size_t)NELEM;
  unsigned short* Vt  = Klo + (size_t)NELEM;

  prep_split_k<<<1024, 256, 0, stream>>>(K, Khi, Klo);
  prep_transpose_v<<<BH*32, 256, 0, stream>>>(V, Vt);
  attn_fused<<<NTILE, 256, 0, stream>>>(Q, Khi, Klo, Vt, ctx_out, attn_out);
}